// Round 1
// baseline (475.864 us; speedup 1.0000x reference)
//
#include <hip/hip_runtime.h>
#include <cstddef>

#define NB 128
#define NT 4096
#define NV 128
#define NH 256
#define N4H 1024
#define NC 10

// One workgroup per batch sample. 1024 threads:
//   q = tid>>8  (0..3)  : K-dimension quarter (split dot-product)
//   j = tid&255 (0..255): column group, owns z columns 4j..4j+3 (float4 loads of W rows)
// Gate/update phase uses threads 0..255 (thread e owns h[e], c[e] with c in a register).
// Early exit: once all 10 preds elements of this sample are nonzero, no future step can
// change the output (where(preds==0, logits_last, preds) == preds), so the WG stops.
__global__ __launch_bounds__(1024, 1)
void earliest_rnn_kernel(const float* __restrict__ X,
                         const float* __restrict__ U,
                         const float* __restrict__ Wk,
                         const float* __restrict__ Wr,
                         const float* __restrict__ b_lstm,
                         const float* __restrict__ Wo,
                         const float* __restrict__ bo,
                         const float* __restrict__ Wc,
                         const float* __restrict__ bc,
                         float* __restrict__ out)
{
  const int b   = blockIdx.x;
  const int tid = threadIdx.x;
  const int q   = tid >> 8;
  const int j   = tid & 255;

  __shared__ float xs[NV];
  __shared__ float hs[NH];
  __shared__ float zp[4][N4H];      // per-quarter partial z
  __shared__ float wo_s[NH * NC];   // Wo (256x10)
  __shared__ float wc_s[NH + 1];    // Wc (257)
  __shared__ float bl_s[N4H];       // b_lstm
  __shared__ float bo_s[NC];
  __shared__ float red[4][12];      // cross-wave reduction scratch (4 waves x 11 vals)
  __shared__ float logits_s[NC];
  __shared__ float preds_s[NC];
  __shared__ int   flag_s;

  // Preload small weights into LDS (visible after the loop's first barrier).
  for (int i = tid; i < NH * NC; i += 1024) wo_s[i] = Wo[i];
  bl_s[tid] = b_lstm[tid];
  if (tid < NH + 1) wc_s[tid] = Wc[tid];
  if (tid < NC) { bo_s[tid] = bo[tid]; preds_s[tid] = 0.0f; logits_s[tid] = 0.0f; }
  if (tid < NH) hs[tid] = 0.0f;
  float c_reg = 0.0f;
  const float bc0 = bc[0];

  const float4* Wk4 = reinterpret_cast<const float4*>(Wk);
  const float4* Wr4 = reinterpret_cast<const float4*>(Wr);

  int t = 0;
  for (;;) {
    // ---- stage x_t ----
    if (tid < NV) xs[tid] = X[((size_t)b * NT + t) * NV + tid];
    __syncthreads();  // xs + hs (from prev step) visible

    // ---- z partial: quarter q of (x_t @ Wk + h @ Wr), cols 4j..4j+3 ----
    float ax = 0.f, ay = 0.f, az = 0.f, aw = 0.f;
    {
      const int k0 = q * 32;
      #pragma unroll
      for (int k = 0; k < 32; ++k) {
        const float v = xs[k0 + k];                      // LDS broadcast
        const float4 w = Wk4[(size_t)(k0 + k) * 256 + j]; // coalesced dwordx4
        ax += v * w.x; ay += v * w.y; az += v * w.z; aw += v * w.w;
      }
    }
    {
      const int k0 = q * 64;
      #pragma unroll
      for (int k = 0; k < 64; ++k) {
        const float v = hs[k0 + k];
        const float4 w = Wr4[(size_t)(k0 + k) * 256 + j];
        ax += v * w.x; ay += v * w.y; az += v * w.z; aw += v * w.w;
      }
    }
    reinterpret_cast<float4*>(zp[q])[j] = make_float4(ax, ay, az, aw);
    __syncthreads();  // zp visible

    // ---- gates + state update + head partials (threads 0..255) ----
    if (tid < NH) {
      const int e = tid;
      const float zi = zp[0][e]     + zp[1][e]     + zp[2][e]     + zp[3][e]     + bl_s[e];
      const float zf = zp[0][e+256] + zp[1][e+256] + zp[2][e+256] + zp[3][e+256] + bl_s[e+256];
      const float zg = zp[0][e+512] + zp[1][e+512] + zp[2][e+512] + zp[3][e+512] + bl_s[e+512];
      const float zo = zp[0][e+768] + zp[1][e+768] + zp[2][e+768] + zp[3][e+768] + bl_s[e+768];
      const float gi = 1.0f / (1.0f + expf(-zi));
      const float gf = 1.0f / (1.0f + expf(-zf));
      const float gg = tanhf(zg);
      const float go = 1.0f / (1.0f + expf(-zo));
      c_reg = gf * c_reg + gi * gg;
      const float h = go * tanhf(c_reg);
      hs[e] = h;  // safe: nobody reads hs until next iteration's first barrier

      // partials: 10 logit columns + p dot
      float part[11];
      #pragma unroll
      for (int cc = 0; cc < NC; ++cc) part[cc] = h * wo_s[e * NC + cc];
      part[10] = h * wc_s[e];
      #pragma unroll
      for (int off = 32; off > 0; off >>= 1) {
        #pragma unroll
        for (int cc = 0; cc < 11; ++cc)
          part[cc] += __shfl_xor(part[cc], off, 64);
      }
      if ((tid & 63) == 0) {
        const int w = tid >> 6;
        #pragma unroll
        for (int cc = 0; cc < 11; ++cc) red[w][cc] = part[cc];
      }
    }
    __syncthreads();  // red visible

    // ---- softmax, halting draw, preds update (thread 0) ----
    if (tid == 0) {
      float l[NC];
      float m = -1e30f;
      #pragma unroll
      for (int cc = 0; cc < NC; ++cc) {
        l[cc] = red[0][cc] + red[1][cc] + red[2][cc] + red[3][cc] + bo_s[cc];
        m = fmaxf(m, l[cc]);
      }
      float s = 0.f;
      #pragma unroll
      for (int cc = 0; cc < NC; ++cc) { l[cc] = expf(l[cc] - m); s += l[cc]; }
      const float inv  = 1.0f / s;
      const float psum = red[0][10] + red[1][10] + red[2][10] + red[3][10];
      const float pre  = psum + (float)t * wc_s[NH] + bc0;
      const float p    = 1.0f / (1.0f + expf(-pre));
      const float probs = 0.9f * p + 0.005f;          // (1-EPS)*p + EPS*0.05
      const float uv   = U[(size_t)b * NT + t];
      const int a = (uv < probs) ? 1 : 0;
      int done = 1;
      #pragma unroll
      for (int cc = 0; cc < NC; ++cc) {
        const float lg = l[cc] * inv;
        logits_s[cc] = lg;
        if (a && preds_s[cc] == 0.0f) preds_s[cc] = lg;
        if (preds_s[cc] == 0.0f) done = 0;
      }
      flag_s = (done || (t == NT - 1)) ? 1 : 0;
    }
    __syncthreads();  // flag_s, preds_s, logits_s visible
    if (flag_s) break;
    ++t;
  }

  // output: where(preds==0, logits_last, preds)
  if (tid < NC) {
    const float pv = preds_s[tid];
    out[b * NC + tid] = (pv != 0.0f) ? pv : logits_s[tid];
  }
}

extern "C" void kernel_launch(void* const* d_in, const int* in_sizes, int n_in,
                              void* d_out, int out_size, void* d_ws, size_t ws_size,
                              hipStream_t stream)
{
  const float* X  = (const float*)d_in[0];
  const float* U  = (const float*)d_in[1];
  const float* Wk = (const float*)d_in[2];
  const float* Wr = (const float*)d_in[3];
  const float* bl = (const float*)d_in[4];
  const float* Wo = (const float*)d_in[5];
  const float* bo = (const float*)d_in[6];
  const float* Wc = (const float*)d_in[7];
  const float* bc = (const float*)d_in[8];
  float* out = (float*)d_out;

  hipLaunchKernelGGL(earliest_rnn_kernel, dim3(NB), dim3(1024), 0, stream,
                     X, U, Wk, Wr, bl, Wo, bo, Wc, bc, out);
}

// Round 2
// 326.015 us; speedup vs baseline: 1.4596x; 1.4596x over previous
//
#include <hip/hip_runtime.h>
#include <cstddef>
#include <cstdint>

#define NT_ 4096
#define NV_ 128
#define NH_ 256
#define NC_ 10
#define KT_ 384            // NV_ + NH_
#define NGRP 16            // sample groups
#define SB   8             // samples per group
#define GWG  16            // workgroups per group
#define TPW  256
#define VST  12            // v_lds row stride (floats), 16B-aligned, bank-clean
#define Z9   9             // zp row pad (float4s)
#define FULLMASK 255

// dynamic LDS partition (float offsets)
#define SM_W    0
#define SM_V    24576                    // KT_*64 weights
#define SM_ZP   (SM_V + KT_*VST)         // 29184
#define SM_C    (SM_ZP + 2304)           // 31488  c[16][9]
#define SM_BL   (SM_C + 144)             // 31632  bias slice [64]
#define SM_WO   (SM_BL + 64)             // 31696  leader Wo' [256][11]
#define SM_ZPH  (SM_WO + 2816)           // 34512  head wave partials [4][8][12]
#define SM_HD   (SM_ZPH + 384)           // 34896  bo[10], wc_t, bc0
#define SM_TOT  (SM_HD + 12)             // 34908 floats
#define SMEM_BYTES (SM_TOT * 4)          // 139632 B

// d_ws layout: cnt[16] @ stride 256B -> 4096 B ; gmask[16] @ stride 256B -> 4096 B ; hbuf[2][16][256][8] floats
#define WS_GMASK 4096
#define WS_HBUF  8192

#define FMA8(S) \
  acc[S].x = fmaf(w4.x, vs, acc[S].x); \
  acc[S].y = fmaf(w4.y, vs, acc[S].y); \
  acc[S].z = fmaf(w4.z, vs, acc[S].z); \
  acc[S].w = fmaf(w4.w, vs, acc[S].w);

extern "C" __global__ __launch_bounds__(TPW, 1)
void earliest_coop(const float* __restrict__ X, const float* __restrict__ U,
                   const float* __restrict__ Wk, const float* __restrict__ Wr,
                   const float* __restrict__ bl, const float* __restrict__ Wo,
                   const float* __restrict__ bo, const float* __restrict__ Wc,
                   const float* __restrict__ bc, float* __restrict__ out,
                   int* __restrict__ cnt, int* __restrict__ gmask,
                   float* __restrict__ hbuf)
{
  extern __shared__ float smem[];
  float* w_lds = smem + SM_W;
  float* v_lds = smem + SM_V;
  float* zp    = smem + SM_ZP;
  float* c_lds = smem + SM_C;
  float* bl_s  = smem + SM_BL;
  float* wo_s  = smem + SM_WO;
  float* zph   = smem + SM_ZPH;
  float* hd_s  = smem + SM_HD;
  __shared__ int mask_lds;     // last synced group halt mask
  __shared__ int halted_lds;   // leader's running halt mask

  const int tid  = threadIdx.x;
  const int w    = blockIdx.x & 15;   // WG within group
  const int g    = blockIdx.x >> 4;   // group
  const int colq = tid & 15;          // col-quad within WG (16 x float4 = 64 cols)
  const int ks   = tid >> 4;          // K-split 0..15
  const bool leader = (w == 0);

  // ---- one-time: stage weight slice into LDS (swizzled) ----
  for (int m = 0; m < 24; ++m) {
    int idx4 = m * 256 + tid;
    int k = idx4 >> 4, cq = idx4 & 15;
    int rr = cq >> 2, qq = cq & 3;
    int col4 = rr * 64 + w * 4 + qq;            // float4 column index in [0,256)
    float4 wv;
    if (k < NV_) wv = ((const float4*)Wk)[(size_t)k * 256 + col4];
    else         wv = ((const float4*)Wr)[(size_t)(k - NV_) * 256 + col4];
    ((float4*)w_lds)[k * 16 + (cq ^ (k & 7))] = wv;
  }
  if (tid < 64) {
    int rr = tid >> 4, e = tid & 15;
    bl_s[tid] = bl[rr * 256 + w * 16 + e];
  }
  if (tid < 128) c_lds[(tid >> 3) * Z9 + (tid & 7)] = 0.f;
  if (leader) {
    for (int m = tid; m < 2816; m += TPW) {
      int e = m / 11, cc = m % 11;
      wo_s[m] = (cc < 10) ? Wo[e * 10 + cc] : Wc[e];
    }
    if (tid < 10)  hd_s[tid] = bo[tid];
    if (tid == 10) hd_s[10] = Wc[256];
    if (tid == 11) hd_s[11] = bc[0];
    if (tid == 0)  halted_lds = 0;
  }
  if (tid == 0) mask_lds = 0;
  __syncthreads();

  int* cntg = cnt + (g << 6);
  int* gmg  = gmask + (g << 6);
  const int cswz  = colq ^ (ks & 7);
  const int wbase = ks * 16 + cswz;

  for (int it = 0;; ++it) {
    // ---- leader head: reference step tau = it-1, uses h_it in hbuf[it&1] ----
    if (leader && it >= 1 && halted_lds != FULLMASK) {
      const float* hsrc = hbuf + ((size_t)(it & 1) * NGRP + g) * NH_ * SB;
      float acc[11];
      #pragma unroll
      for (int cc = 0; cc < 11; ++cc) acc[cc] = 0.f;
      int e5 = tid >> 3, s = tid & 7;
      #pragma unroll
      for (int i2 = 0; i2 < 8; ++i2) {
        int e = i2 * 32 + e5;
        float hv = __hip_atomic_load(hsrc + i2 * 256 + tid, __ATOMIC_RELAXED, __HIP_MEMORY_SCOPE_AGENT);
        #pragma unroll
        for (int cc = 0; cc < 11; ++cc) acc[cc] += hv * wo_s[e * 11 + cc];
      }
      #pragma unroll
      for (int off = 8; off <= 32; off <<= 1) {
        #pragma unroll
        for (int cc = 0; cc < 11; ++cc) acc[cc] += __shfl_xor(acc[cc], off, 64);
      }
      if ((tid & 63) < 8) {
        int w4 = tid >> 6;
        #pragma unroll
        for (int cc = 0; cc < 11; ++cc) zph[(w4 * 8 + s) * 12 + cc] = acc[cc];
      }
      __syncthreads();
      if (tid < 8) {
        int s_ = tid;
        if (!((halted_lds >> s_) & 1)) {
          float zs[11];
          #pragma unroll
          for (int cc = 0; cc < 11; ++cc)
            zs[cc] = zph[(0 * 8 + s_) * 12 + cc] + zph[(1 * 8 + s_) * 12 + cc]
                   + zph[(2 * 8 + s_) * 12 + cc] + zph[(3 * 8 + s_) * 12 + cc];
          float l[10]; float mx = -1e30f;
          #pragma unroll
          for (int cc = 0; cc < 10; ++cc) { l[cc] = zs[cc] + hd_s[cc]; mx = fmaxf(mx, l[cc]); }
          float ssum = 0.f;
          #pragma unroll
          for (int cc = 0; cc < 10; ++cc) { l[cc] = expf(l[cc] - mx); ssum += l[cc]; }
          float inv = 1.f / ssum;
          int tau = it - 1;
          float pre = zs[10] + (float)tau * hd_s[10] + hd_s[11];
          float p = 1.f / (1.f + expf(-pre));
          float probs = 0.9f * p + 0.005f;
          float uv = U[(size_t)(g * SB + s_) * NT_ + tau];
          bool a = (uv < probs);
          if (a || it == NT_) {
            float* op = out + (g * SB + s_) * NC_;
            #pragma unroll
            for (int cc = 0; cc < 10; ++cc) op[cc] = l[cc] * inv;
          }
          if (a) atomicOr(&halted_lds, 1 << s_);
        }
      }
      __syncthreads();
    }
    if (it == NT_) break;
    if (mask_lds == FULLMASK) break;

    // ---- stage v = [x_it ; h_it] into LDS, layout [k][s] stride VST ----
    {
      const float* hsrc = hbuf + ((size_t)(it & 1) * NGRP + g) * NH_ * SB;
      #pragma unroll
      for (int i2 = 0; i2 < 4; ++i2) {
        int flat = i2 * 256 + tid;
        int k = flat >> 3, s = flat & 7;
        float xv = X[((size_t)(g * SB + s) * NT_ + it) * NV_ + k];
        v_lds[k * VST + s] = xv;
      }
      if (it == 0) {
        #pragma unroll
        for (int i2 = 0; i2 < 8; ++i2) {
          int flat = i2 * 256 + tid;
          v_lds[(NV_ + (flat >> 3)) * VST + (flat & 7)] = 0.f;
        }
      } else {
        #pragma unroll
        for (int i2 = 0; i2 < 8; ++i2) {
          int flat = i2 * 256 + tid;
          float hv = __hip_atomic_load(hsrc + flat, __ATOMIC_RELAXED, __HIP_MEMORY_SCOPE_AGENT);
          v_lds[(NV_ + (flat >> 3)) * VST + (flat & 7)] = hv;
        }
      }
    }
    __syncthreads();

    // ---- z slice: 64 cols x 8 samples, K split 16-way ----
    float4 acc[8];
    #pragma unroll
    for (int s = 0; s < 8; ++s) acc[s] = make_float4(0.f, 0.f, 0.f, 0.f);
    {
      const float4* wl4 = (const float4*)w_lds;
      #pragma unroll
      for (int i = 0; i < 24; ++i) {
        int k = i * 16 + ks;
        float4 w4 = wl4[i * 256 + wbase];
        const float* vk = v_lds + k * VST;
        float4 va = *(const float4*)(vk);
        float4 vb = *(const float4*)(vk + 4);
        { float vs = va.x; FMA8(0) } { float vs = va.y; FMA8(1) }
        { float vs = va.z; FMA8(2) } { float vs = va.w; FMA8(3) }
        { float vs = vb.x; FMA8(4) } { float vs = vb.y; FMA8(5) }
        { float vs = vb.z; FMA8(6) } { float vs = vb.w; FMA8(7) }
      }
    }
    // reduce over ks&3 (lane bits 4,5)
    #pragma unroll
    for (int off = 16; off <= 32; off <<= 1) {
      #pragma unroll
      for (int s = 0; s < 8; ++s) {
        acc[s].x += __shfl_xor(acc[s].x, off, 64);
        acc[s].y += __shfl_xor(acc[s].y, off, 64);
        acc[s].z += __shfl_xor(acc[s].z, off, 64);
        acc[s].w += __shfl_xor(acc[s].w, off, 64);
      }
    }
    if ((tid & 48) == 0) {   // ks&3 == 0 lanes
      int w4 = tid >> 6;
      float4* zp4 = (float4*)zp;
      #pragma unroll
      for (int s = 0; s < 8; ++s) zp4[(w4 * 16 + colq) * Z9 + s] = acc[s];
    }
    __syncthreads();

    // ---- gates + state update + h write (threads 0..127: e x s) ----
    if (tid < 128) {
      int e = tid >> 3, s = tid & 7;
      float zg4[4];
      #pragma unroll
      for (int r = 0; r < 4; ++r) {
        int cq = r * 4 + (e >> 2);
        int j  = e & 3;
        float sum = 0.f;
        #pragma unroll
        for (int w4 = 0; w4 < 4; ++w4)
          sum += zp[((w4 * 16 + cq) * Z9 + s) * 4 + j];
        zg4[r] = sum + bl_s[r * 16 + e];
      }
      float gi = 1.f / (1.f + expf(-zg4[0]));
      float gf = 1.f / (1.f + expf(-zg4[1]));
      float gg = tanhf(zg4[2]);
      float go = 1.f / (1.f + expf(-zg4[3]));
      float c = gf * c_lds[e * Z9 + s] + gi * gg;
      c_lds[e * Z9 + s] = c;
      float h = go * tanhf(c);
      size_t hidx = (((size_t)((it + 1) & 1) * NGRP + g) * NH_ + (w * 16 + e)) * SB + s;
      __hip_atomic_store(hbuf + hidx, h, __ATOMIC_RELAXED, __HIP_MEMORY_SCOPE_AGENT);
    }
    // ---- publish mask (leader), then group sync ----
    if (leader && tid == 0)
      __hip_atomic_store(gmg, halted_lds, __ATOMIC_RELAXED, __HIP_MEMORY_SCOPE_AGENT);
    __syncthreads();
    if (tid == 0) {
      __threadfence();                       // release h writes + mask
      atomicAdd(cntg, 1);
      int target = GWG * (it + 1);
      while (__hip_atomic_load(cntg, __ATOMIC_ACQUIRE, __HIP_MEMORY_SCOPE_AGENT) < target)
        __builtin_amdgcn_s_sleep(2);
      __threadfence();                       // acquire
      mask_lds = __hip_atomic_load(gmg, __ATOMIC_RELAXED, __HIP_MEMORY_SCOPE_AGENT);
    }
    __syncthreads();
    __threadfence();                         // per-thread acquire before next hbuf reads
  }
}

extern "C" void kernel_launch(void* const* d_in, const int* in_sizes, int n_in,
                              void* d_out, int out_size, void* d_ws, size_t ws_size,
                              hipStream_t stream)
{
  const float* X  = (const float*)d_in[0];
  const float* U  = (const float*)d_in[1];
  const float* Wk = (const float*)d_in[2];
  const float* Wr = (const float*)d_in[3];
  const float* bL = (const float*)d_in[4];
  const float* Wo = (const float*)d_in[5];
  const float* bo = (const float*)d_in[6];
  const float* Wc = (const float*)d_in[7];
  const float* bc = (const float*)d_in[8];
  float* out = (float*)d_out;

  int*   cnt   = (int*)d_ws;
  int*   gmask = (int*)((char*)d_ws + WS_GMASK);
  float* hbuf  = (float*)((char*)d_ws + WS_HBUF);

  hipMemsetAsync(d_ws, 0, WS_HBUF, stream);   // zero cnt + gmask each call

  hipFuncSetAttribute((const void*)earliest_coop,
                      hipFuncAttributeMaxDynamicSharedMemorySize, SMEM_BYTES);

  void* args[] = { (void*)&X, (void*)&U, (void*)&Wk, (void*)&Wr, (void*)&bL,
                   (void*)&Wo, (void*)&bo, (void*)&Wc, (void*)&bc, (void*)&out,
                   (void*)&cnt, (void*)&gmask, (void*)&hbuf };
  hipLaunchCooperativeKernel((const void*)earliest_coop, dim3(NGRP * GWG), dim3(TPW),
                             args, SMEM_BYTES, stream);
}

// Round 7
// 305.382 us; speedup vs baseline: 1.5583x; 1.0676x over previous
//
#include <hip/hip_runtime.h>
#include <cstddef>
#include <cstdint>

#define NT_ 4096
#define NV_ 128
#define NH_ 256
#define NC_ 10
#define KT_ 384            // NV_ + NH_
#define NGRP 16            // sample groups
#define SB   8             // samples per group
#define GWG  16            // workgroups per group
#define TPW  256
#define VST  12            // v_lds row stride (floats), 16B-aligned, bank-clean
#define Z9   9             // zp row pad (float4s)
#define FULLMASK 255

// dynamic LDS partition (float offsets)
#define SM_W    0                        // 24576: weight slice (96KB)
#define SM_V    24576                    // 4608:  v = [x;h] rows [384][VST]
#define SM_ZP   (SM_V + KT_*VST)         // 29184: zp 64*Z9 float4 = 2304 (also leader head scratch)
#define SM_C    (SM_ZP + 2304)           // 31488: c[16][Z9]
#define SM_BL   (SM_C + 144)             // 31632: bias slice [64]
#define SM_WC   (SM_BL + 64)             // 31696: full Wc [257] (every WG)
#define SM_WO   (SM_WC + 260)            // 31956: leader Wo [256*10]
#define SM_HD   (SM_WO + 2560)           // 34516: bo[10], bc0
#define SM_RED  (SM_HD + 12)             // 34528: head wave partials [4][8]
#define SM_TOT  (SM_RED + 32)            // 34560 floats
#define SMEM_BYTES (SM_TOT * 4)          // 138240 B

// d_ws layout: cnt[16] @ stride 256B -> 4096 B ; hbuf[2][16][256][8] floats
#define WS_HBUF  4096

#define ALD(p)    __hip_atomic_load((p), __ATOMIC_RELAXED, __HIP_MEMORY_SCOPE_AGENT)
#define AST(p,v)  __hip_atomic_store((p), (v), __ATOMIC_RELAXED, __HIP_MEMORY_SCOPE_AGENT)

#define FMA8(S) \
  acc[S].x = fmaf(w4.x, vs, acc[S].x); \
  acc[S].y = fmaf(w4.y, vs, acc[S].y); \
  acc[S].z = fmaf(w4.z, vs, acc[S].z); \
  acc[S].w = fmaf(w4.w, vs, acc[S].w);

extern "C" __global__ __launch_bounds__(TPW, 1)
void earliest_coop(const float* __restrict__ X, const float* __restrict__ U,
                   const float* __restrict__ Wk, const float* __restrict__ Wr,
                   const float* __restrict__ bl, const float* __restrict__ Wo,
                   const float* __restrict__ bo, const float* __restrict__ Wc,
                   const float* __restrict__ bc, float* __restrict__ out,
                   int* __restrict__ cnt, float* __restrict__ hbuf)
{
  extern __shared__ float smem[];
  float* w_lds = smem + SM_W;
  float* v_lds = smem + SM_V;
  float* zp    = smem + SM_ZP;
  float* c_lds = smem + SM_C;
  float* bl_s  = smem + SM_BL;
  float* wc_s  = smem + SM_WC;
  float* wo_s  = smem + SM_WO;
  float* hd_s  = smem + SM_HD;
  float* red   = smem + SM_RED;
  __shared__ int halted_lds;   // replicated (deterministic, identical in all WGs)
  __shared__ int wflags;       // samples needing an out-write this iter

  const int tid  = threadIdx.x;
  const int w    = blockIdx.x & 15;   // WG within group
  const int g    = blockIdx.x >> 4;   // group
  const int colq = tid & 15;          // col-quad within WG (16 x float4 = 64 cols)
  const int ks   = tid >> 4;          // K-split 0..15
  const bool leader = (w == 0);

  // ---- one-time: stage weight slice into LDS (swizzled) ----
  for (int m = 0; m < 24; ++m) {
    int idx4 = m * 256 + tid;
    int k = idx4 >> 4, cq = idx4 & 15;
    int rr = cq >> 2, qq = cq & 3;
    int col4 = rr * 64 + w * 4 + qq;            // float4 column index in [0,256)
    float4 wv;
    if (k < NV_) wv = ((const float4*)Wk)[(size_t)k * 256 + col4];
    else         wv = ((const float4*)Wr)[(size_t)(k - NV_) * 256 + col4];
    ((float4*)w_lds)[k * 16 + (cq ^ (k & 7))] = wv;
  }
  if (tid < 64) {
    int rr = tid >> 4, e = tid & 15;
    bl_s[tid] = bl[rr * 256 + w * 16 + e];
  }
  wc_s[tid] = Wc[tid];
  if (tid == 0) wc_s[256] = Wc[256];
  if (tid < 128) c_lds[(tid >> 3) * Z9 + (tid & 7)] = 0.f;
  if (leader) {
    for (int m = tid; m < NH_ * NC_; m += TPW) wo_s[m] = Wo[m];
  }
  if (tid < 10)  hd_s[tid] = bo[tid];
  if (tid == 10) hd_s[10] = bc[0];
  if (tid == 0)  { halted_lds = 0; wflags = 0; }
  __syncthreads();

  int* cntg = cnt + (g << 6);
  const int cswz  = colq ^ (ks & 7);
  const int wbase = ks * 16 + cswz;

  for (int it = 0;; ++it) {
    // ---- stage v = [x_it ; h_{it-1}] into LDS, layout [k][s] stride VST ----
    if (tid == 0) wflags = 0;
    if (it < NT_) {
      #pragma unroll
      for (int i2 = 0; i2 < 4; ++i2) {
        int flat = i2 * 256 + tid;
        int k = flat >> 3, s = flat & 7;
        v_lds[k * VST + s] = X[((size_t)(g * SB + s) * NT_ + it) * NV_ + k];
      }
    }
    if (it == 0) {
      #pragma unroll
      for (int i2 = 0; i2 < 8; ++i2) {
        int flat = i2 * 256 + tid;
        v_lds[(NV_ + (flat >> 3)) * VST + (flat & 7)] = 0.f;
      }
    } else {
      const float* hsrc = hbuf + ((size_t)(it & 1) * NGRP + g) * NH_ * SB;
      #pragma unroll
      for (int i2 = 0; i2 < 8; ++i2) {
        int flat = i2 * 256 + tid;
        v_lds[(NV_ + (flat >> 3)) * VST + (flat & 7)] = ALD(hsrc + flat);
      }
    }
    __syncthreads();   // B1: v_lds + wflags reset visible

    // ---- replicated halting head for tau = it-1 (every WG, identical bits) ----
    if (it >= 1) {
      {
        const float* hv = v_lds + (NV_ + tid) * VST;   // h_tau[e=tid][s]
        const float wcv = wc_s[tid];
        float part[SB];
        #pragma unroll
        for (int s = 0; s < SB; ++s) part[s] = hv[s] * wcv;
        #pragma unroll
        for (int off = 1; off <= 32; off <<= 1) {
          #pragma unroll
          for (int s = 0; s < SB; ++s) part[s] += __shfl_xor(part[s], off, 64);
        }
        if ((tid & 63) == 0) {
          int w4 = tid >> 6;
          #pragma unroll
          for (int s = 0; s < SB; ++s) red[w4 * 8 + s] = part[s];
        }
      }
      __syncthreads();   // B2: red visible

      if (tid < SB) {
        const int s_ = tid;
        if (!((halted_lds >> s_) & 1)) {
          const int tau = it - 1;
          const float psum = red[0 * 8 + s_] + red[1 * 8 + s_] + red[2 * 8 + s_] + red[3 * 8 + s_];
          const float pre   = psum + (float)tau * wc_s[256] + hd_s[10];
          const float p     = 1.f / (1.f + expf(-pre));
          const float probs = 0.9f * p + 0.005f;
          const float uv    = U[(size_t)(g * SB + s_) * NT_ + tau];
          const bool  a     = (uv < probs);
          if (a || tau == NT_ - 1) atomicOr(&wflags, 1 << s_);
          if (a) atomicOr(&halted_lds, 1 << s_);
        }
      }
      __syncthreads();   // B3: halted_lds / wflags visible

      // ---- leader-only: logits + softmax + out write for flagged samples (rare) ----
      if (leader && wflags) {
        const int e5 = tid >> 3, s = tid & 7;
        float accv[NC_];
        #pragma unroll
        for (int cc = 0; cc < NC_; ++cc) accv[cc] = 0.f;
        #pragma unroll
        for (int i2 = 0; i2 < 8; ++i2) {
          const int e = i2 * 32 + e5;
          const float hvv = v_lds[(NV_ + e) * VST + s];
          #pragma unroll
          for (int cc = 0; cc < NC_; ++cc) accv[cc] += hvv * wo_s[e * NC_ + cc];
        }
        #pragma unroll
        for (int off = 8; off <= 32; off <<= 1) {
          #pragma unroll
          for (int cc = 0; cc < NC_; ++cc) accv[cc] += __shfl_xor(accv[cc], off, 64);
        }
        if ((tid & 56) == 0) {
          const int w4 = tid >> 6;
          #pragma unroll
          for (int cc = 0; cc < NC_; ++cc) zp[(w4 * 8 + s) * NC_ + cc] = accv[cc];
        }
        __syncthreads();   // B4 (leader WG only)
        if (tid < SB && ((wflags >> tid) & 1)) {
          const int s_ = tid;
          float l[NC_];
          float mx = -1e30f;
          #pragma unroll
          for (int cc = 0; cc < NC_; ++cc) {
            l[cc] = zp[(0 * 8 + s_) * NC_ + cc] + zp[(1 * 8 + s_) * NC_ + cc]
                  + zp[(2 * 8 + s_) * NC_ + cc] + zp[(3 * 8 + s_) * NC_ + cc] + hd_s[cc];
            mx = fmaxf(mx, l[cc]);
          }
          float ssum = 0.f;
          #pragma unroll
          for (int cc = 0; cc < NC_; ++cc) { l[cc] = expf(l[cc] - mx); ssum += l[cc]; }
          const float inv = 1.f / ssum;
          float* op = out + (g * SB + s_) * NC_;
          #pragma unroll
          for (int cc = 0; cc < NC_; ++cc) op[cc] = l[cc] * inv;
        }
        __syncthreads();   // B4b (leader WG only): zp free before z-phase
      }
    }

    if (halted_lds == FULLMASK || it == NT_) break;   // identical decision in all WGs

    // ---- z slice: 64 cols x 8 samples, K split 16-way (round-2 verbatim) ----
    float4 acc[8];
    #pragma unroll
    for (int s = 0; s < 8; ++s) acc[s] = make_float4(0.f, 0.f, 0.f, 0.f);
    {
      const float4* wl4 = (const float4*)w_lds;
      #pragma unroll
      for (int i = 0; i < 24; ++i) {
        int k = i * 16 + ks;
        float4 w4 = wl4[i * 256 + wbase];
        const float* vk = v_lds + k * VST;
        float4 va = *(const float4*)(vk);
        float4 vb = *(const float4*)(vk + 4);
        { float vs = va.x; FMA8(0) } { float vs = va.y; FMA8(1) }
        { float vs = va.z; FMA8(2) } { float vs = va.w; FMA8(3) }
        { float vs = vb.x; FMA8(4) } { float vs = vb.y; FMA8(5) }
        { float vs = vb.z; FMA8(6) } { float vs = vb.w; FMA8(7) }
      }
    }
    #pragma unroll
    for (int off = 16; off <= 32; off <<= 1) {
      #pragma unroll
      for (int s = 0; s < 8; ++s) {
        acc[s].x += __shfl_xor(acc[s].x, off, 64);
        acc[s].y += __shfl_xor(acc[s].y, off, 64);
        acc[s].z += __shfl_xor(acc[s].z, off, 64);
        acc[s].w += __shfl_xor(acc[s].w, off, 64);
      }
    }
    if ((tid & 48) == 0) {   // ks&3 == 0 lanes
      int w4 = tid >> 6;
      float4* zp4 = (float4*)zp;
      #pragma unroll
      for (int s = 0; s < 8; ++s) zp4[(w4 * 16 + colq) * Z9 + s] = acc[s];
    }
    __syncthreads();   // B5: zp visible

    // ---- gates + state update + h write (threads 0..127: e x s) ----
    if (tid < 128) {
      int e = tid >> 3, s = tid & 7;
      float zg4[4];
      #pragma unroll
      for (int r = 0; r < 4; ++r) {
        int cq = r * 4 + (e >> 2);
        int j  = e & 3;
        float sum = 0.f;
        #pragma unroll
        for (int w4 = 0; w4 < 4; ++w4)
          sum += zp[((w4 * 16 + cq) * Z9 + s) * 4 + j];
        zg4[r] = sum + bl_s[r * 16 + e];
      }
      float gi = 1.f / (1.f + expf(-zg4[0]));
      float gf = 1.f / (1.f + expf(-zg4[1]));
      float gg = tanhf(zg4[2]);
      float go = 1.f / (1.f + expf(-zg4[3]));
      float c = gf * c_lds[e * Z9 + s] + gi * gg;
      c_lds[e * Z9 + s] = c;
      float h = go * tanhf(c);
      size_t hidx = (((size_t)((it + 1) & 1) * NGRP + g) * NH_ + (w * 16 + e)) * SB + s;
      AST(hbuf + hidx, h);
    }
    __syncthreads();   // B6: h stores issued before sync

    // ---- group sync: round-2 verbatim (minus gmask) ----
    if (tid == 0) {
      __threadfence();                       // release h writes
      atomicAdd(cntg, 1);
      int target = GWG * (it + 1);
      while (__hip_atomic_load(cntg, __ATOMIC_ACQUIRE, __HIP_MEMORY_SCOPE_AGENT) < target)
        __builtin_amdgcn_s_sleep(2);
      __threadfence();                       // acquire
    }
    __syncthreads();   // B7
    __threadfence();                         // per-thread acquire before next hbuf reads
  }
}

extern "C" void kernel_launch(void* const* d_in, const int* in_sizes, int n_in,
                              void* d_out, int out_size, void* d_ws, size_t ws_size,
                              hipStream_t stream)
{
  const float* X  = (const float*)d_in[0];
  const float* U  = (const float*)d_in[1];
  const float* Wk = (const float*)d_in[2];
  const float* Wr = (const float*)d_in[3];
  const float* bL = (const float*)d_in[4];
  const float* Wo = (const float*)d_in[5];
  const float* bo = (const float*)d_in[6];
  const float* Wc = (const float*)d_in[7];
  const float* bc = (const float*)d_in[8];
  float* out = (float*)d_out;

  int*   cnt  = (int*)d_ws;
  float* hbuf = (float*)((char*)d_ws + WS_HBUF);

  hipMemsetAsync(d_ws, 0, WS_HBUF, stream);   // zero counters each call

  hipFuncSetAttribute((const void*)earliest_coop,
                      hipFuncAttributeMaxDynamicSharedMemorySize, SMEM_BYTES);

  void* args[] = { (void*)&X, (void*)&U, (void*)&Wk, (void*)&Wr, (void*)&bL,
                   (void*)&Wo, (void*)&bo, (void*)&Wc, (void*)&bc, (void*)&out,
                   (void*)&cnt, (void*)&hbuf };
  hipError_t lerr = hipLaunchCooperativeKernel((const void*)earliest_coop,
                                               dim3(NGRP * GWG), dim3(TPW),
                                               args, SMEM_BYTES, stream);
  if (lerr != hipSuccess) {
    // Fallback: plain launch. grid=256 WGs x ~135KB LDS -> 1 WG/CU on 256 CUs,
    // all co-resident in practice; same spin-sync semantics.
    hipLaunchKernelGGL(earliest_coop, dim3(NGRP * GWG), dim3(TPW), SMEM_BYTES, stream,
                       X, U, Wk, Wr, bL, Wo, bo, Wc, bc, out, cnt, hbuf);
  }
}

// Round 8
// 182.147 us; speedup vs baseline: 2.6125x; 1.6766x over previous
//
#include <hip/hip_runtime.h>
#include <cstddef>
#include <cstdint>

#define NT_ 4096
#define NV_ 128
#define NH_ 256
#define NC_ 10
#define KT_ 384            // NV_ + NH_
#define NGRP 16            // sample groups
#define SB   8             // samples per group
#define GWG  16            // workgroups per group
#define TPW  256
#define VST  12            // v_lds row stride (floats), 16B-aligned, bank-clean
#define Z9   9             // zp row pad (float4s)
#define FULLMASK 255

// dynamic LDS partition (float offsets)
#define SM_W    0                        // 24576: weight slice (96KB)
#define SM_V    24576                    // 4608:  v = [x;h] rows [384][VST]
#define SM_ZP   (SM_V + KT_*VST)         // 29184: zp 64*Z9 float4 = 2304 (also leader head scratch)
#define SM_C    (SM_ZP + 2304)           // 31488: c[16][Z9]
#define SM_BL   (SM_C + 144)             // 31632: bias slice [64]
#define SM_WC   (SM_BL + 64)             // 31696: full Wc [257] (every WG)
#define SM_WO   (SM_WC + 260)            // 31956: leader Wo [256*10]
#define SM_HD   (SM_WO + 2560)           // 34516: bo[10], bc0
#define SM_RED  (SM_HD + 12)             // 34528: head wave partials [4][8]
#define SM_TOT  (SM_RED + 32)            // 34560 floats
#define SMEM_BYTES (SM_TOT * 4)          // 138240 B

// d_ws layout: cnt[16] @ stride 256B -> 4096 B ; hbuf[2][16][256][8] floats
#define WS_HBUF  4096

#define ALD(p)    __hip_atomic_load((p), __ATOMIC_RELAXED, __HIP_MEMORY_SCOPE_AGENT)
#define AST(p,v)  __hip_atomic_store((p), (v), __ATOMIC_RELAXED, __HIP_MEMORY_SCOPE_AGENT)

#define FMA8(S) \
  acc[S].x = fmaf(w4.x, vs, acc[S].x); \
  acc[S].y = fmaf(w4.y, vs, acc[S].y); \
  acc[S].z = fmaf(w4.z, vs, acc[S].z); \
  acc[S].w = fmaf(w4.w, vs, acc[S].w);

extern "C" __global__ __launch_bounds__(TPW, 1)
void earliest_coop(const float* __restrict__ X, const float* __restrict__ U,
                   const float* __restrict__ Wk, const float* __restrict__ Wr,
                   const float* __restrict__ bl, const float* __restrict__ Wo,
                   const float* __restrict__ bo, const float* __restrict__ Wc,
                   const float* __restrict__ bc, float* __restrict__ out,
                   int* __restrict__ cnt, float* __restrict__ hbuf)
{
  extern __shared__ float smem[];
  float* w_lds = smem + SM_W;
  float* v_lds = smem + SM_V;
  float* zp    = smem + SM_ZP;
  float* c_lds = smem + SM_C;
  float* bl_s  = smem + SM_BL;
  float* wc_s  = smem + SM_WC;
  float* wo_s  = smem + SM_WO;
  float* hd_s  = smem + SM_HD;
  float* red   = smem + SM_RED;
  __shared__ int halted_lds;   // replicated (deterministic, identical in all WGs)
  __shared__ int wflags;       // samples needing an out-write this iter

  const int tid  = threadIdx.x;
  const int w    = blockIdx.x & 15;   // WG within group
  const int g    = blockIdx.x >> 4;   // group
  const int colq = tid & 15;          // col-quad within WG (16 x float4 = 64 cols)
  const int ks   = tid >> 4;          // K-split 0..15
  const bool leader = (w == 0);

  // ---- one-time: stage weight slice into LDS (swizzled) ----
  for (int m = 0; m < 24; ++m) {
    int idx4 = m * 256 + tid;
    int k = idx4 >> 4, cq = idx4 & 15;
    int rr = cq >> 2, qq = cq & 3;
    int col4 = rr * 64 + w * 4 + qq;            // float4 column index in [0,256)
    float4 wv;
    if (k < NV_) wv = ((const float4*)Wk)[(size_t)k * 256 + col4];
    else         wv = ((const float4*)Wr)[(size_t)(k - NV_) * 256 + col4];
    ((float4*)w_lds)[k * 16 + (cq ^ (k & 7))] = wv;
  }
  if (tid < 64) {
    int rr = tid >> 4, e = tid & 15;
    bl_s[tid] = bl[rr * 256 + w * 16 + e];
  }
  wc_s[tid] = Wc[tid];
  if (tid == 0) wc_s[256] = Wc[256];
  if (tid < 128) c_lds[(tid >> 3) * Z9 + (tid & 7)] = 0.f;
  if (leader) {
    for (int m = tid; m < NH_ * NC_; m += TPW) wo_s[m] = Wo[m];
  }
  if (tid < 10)  hd_s[tid] = bo[tid];
  if (tid == 10) hd_s[10] = bc[0];
  if (tid == 0)  { halted_lds = 0; wflags = 0; }
  __syncthreads();

  int* cntg = cnt + (g << 6);
  const int cswz  = colq ^ (ks & 7);
  const int wbase = ks * 16 + cswz;

  // X staging decomposition: one float4 per thread per iter
  const int xk4 = tid >> 3;        // 0..31 (float4 row index)
  const int xs  = tid & 7;         // sample
  const float4* X4 = (const float4*)X;
  float4 xr = X4[((size_t)(g * SB + xs) * NT_ + 0) * 32 + xk4];  // prefetch it=0

  for (int it = 0;; ++it) {
    // ---- stage v = [x_it ; h_{it-1}] into LDS, layout [k][s] stride VST ----
    if (tid == 0) wflags = 0;
    if (it < NT_) {
      #pragma unroll
      for (int j = 0; j < 4; ++j)
        v_lds[(4 * xk4 + j) * VST + xs] = ((const float*)&xr)[j];
    }
    if (it == 0) {
      #pragma unroll
      for (int i2 = 0; i2 < 8; ++i2) {
        int flat = i2 * 256 + tid;
        v_lds[(NV_ + (flat >> 3)) * VST + (flat & 7)] = 0.f;
      }
    } else {
      const float* hsrc = hbuf + ((size_t)(it & 1) * NGRP + g) * NH_ * SB;
      #pragma unroll
      for (int i2 = 0; i2 < 8; ++i2) {
        int flat = i2 * 256 + tid;
        v_lds[(NV_ + (flat >> 3)) * VST + (flat & 7)] = ALD(hsrc + flat);
      }
    }
    __syncthreads();   // B1: v_lds + wflags reset visible

    // ---- replicated halting head for tau = it-1 (every WG, identical bits) ----
    if (it >= 1) {
      {
        const float* hv = v_lds + (NV_ + tid) * VST;   // h_tau[e=tid][s]
        const float wcv = wc_s[tid];
        float part[SB];
        #pragma unroll
        for (int s = 0; s < SB; ++s) part[s] = hv[s] * wcv;
        #pragma unroll
        for (int off = 1; off <= 32; off <<= 1) {
          #pragma unroll
          for (int s = 0; s < SB; ++s) part[s] += __shfl_xor(part[s], off, 64);
        }
        if ((tid & 63) == 0) {
          int w4 = tid >> 6;
          #pragma unroll
          for (int s = 0; s < SB; ++s) red[w4 * 8 + s] = part[s];
        }
      }
      __syncthreads();   // B2: red visible

      if (tid < SB) {
        const int s_ = tid;
        if (!((halted_lds >> s_) & 1)) {
          const int tau = it - 1;
          const float psum = red[0 * 8 + s_] + red[1 * 8 + s_] + red[2 * 8 + s_] + red[3 * 8 + s_];
          const float pre   = psum + (float)tau * wc_s[256] + hd_s[10];
          const float p     = 1.f / (1.f + expf(-pre));
          const float probs = 0.9f * p + 0.005f;
          const float uv    = U[(size_t)(g * SB + s_) * NT_ + tau];
          const bool  a     = (uv < probs);
          if (a || tau == NT_ - 1) atomicOr(&wflags, 1 << s_);
          if (a) atomicOr(&halted_lds, 1 << s_);
        }
      }
      __syncthreads();   // B3: halted_lds / wflags visible

      // ---- leader-only: logits + softmax + out write for flagged samples (rare) ----
      if (leader && wflags) {
        const int e5 = tid >> 3, s = tid & 7;
        float accv[NC_];
        #pragma unroll
        for (int cc = 0; cc < NC_; ++cc) accv[cc] = 0.f;
        #pragma unroll
        for (int i2 = 0; i2 < 8; ++i2) {
          const int e = i2 * 32 + e5;
          const float hvv = v_lds[(NV_ + e) * VST + s];
          #pragma unroll
          for (int cc = 0; cc < NC_; ++cc) accv[cc] += hvv * wo_s[e * NC_ + cc];
        }
        #pragma unroll
        for (int off = 8; off <= 32; off <<= 1) {
          #pragma unroll
          for (int cc = 0; cc < NC_; ++cc) accv[cc] += __shfl_xor(accv[cc], off, 64);
        }
        if ((tid & 56) == 0) {
          const int w4 = tid >> 6;
          #pragma unroll
          for (int cc = 0; cc < NC_; ++cc) zp[(w4 * 8 + s) * NC_ + cc] = accv[cc];
        }
        __syncthreads();   // B4 (leader WG only)
        if (tid < SB && ((wflags >> tid) & 1)) {
          const int s_ = tid;
          float l[NC_];
          float mx = -1e30f;
          #pragma unroll
          for (int cc = 0; cc < NC_; ++cc) {
            l[cc] = zp[(0 * 8 + s_) * NC_ + cc] + zp[(1 * 8 + s_) * NC_ + cc]
                  + zp[(2 * 8 + s_) * NC_ + cc] + zp[(3 * 8 + s_) * NC_ + cc] + hd_s[cc];
            mx = fmaxf(mx, l[cc]);
          }
          float ssum = 0.f;
          #pragma unroll
          for (int cc = 0; cc < NC_; ++cc) { l[cc] = expf(l[cc] - mx); ssum += l[cc]; }
          const float inv = 1.f / ssum;
          float* op = out + (g * SB + s_) * NC_;
          #pragma unroll
          for (int cc = 0; cc < NC_; ++cc) op[cc] = l[cc] * inv;
        }
        __syncthreads();   // B4b (leader WG only): zp free before z-phase
      }
    }

    if (halted_lds == FULLMASK || it == NT_) break;   // identical decision in all WGs

    // ---- prefetch X(it+1) into registers (hidden under z-phase) ----
    if (it + 1 < NT_)
      xr = X4[((size_t)(g * SB + xs) * NT_ + (it + 1)) * 32 + xk4];

    // ---- z slice: 64 cols x 8 samples, K split 16-way ----
    float4 acc[8];
    #pragma unroll
    for (int s = 0; s < 8; ++s) acc[s] = make_float4(0.f, 0.f, 0.f, 0.f);
    {
      const float4* wl4 = (const float4*)w_lds;
      #pragma unroll
      for (int i = 0; i < 24; ++i) {
        int k = i * 16 + ks;
        float4 w4 = wl4[i * 256 + wbase];
        const float* vk = v_lds + k * VST;
        float4 va = *(const float4*)(vk);
        float4 vb = *(const float4*)(vk + 4);
        { float vs = va.x; FMA8(0) } { float vs = va.y; FMA8(1) }
        { float vs = va.z; FMA8(2) } { float vs = va.w; FMA8(3) }
        { float vs = vb.x; FMA8(4) } { float vs = vb.y; FMA8(5) }
        { float vs = vb.z; FMA8(6) } { float vs = vb.w; FMA8(7) }
      }
    }
    #pragma unroll
    for (int off = 16; off <= 32; off <<= 1) {
      #pragma unroll
      for (int s = 0; s < 8; ++s) {
        acc[s].x += __shfl_xor(acc[s].x, off, 64);
        acc[s].y += __shfl_xor(acc[s].y, off, 64);
        acc[s].z += __shfl_xor(acc[s].z, off, 64);
        acc[s].w += __shfl_xor(acc[s].w, off, 64);
      }
    }
    if ((tid & 48) == 0) {   // ks&3 == 0 lanes
      int w4 = tid >> 6;
      float4* zp4 = (float4*)zp;
      #pragma unroll
      for (int s = 0; s < 8; ++s) zp4[(w4 * 16 + colq) * Z9 + s] = acc[s];
    }
    __syncthreads();   // B5: zp visible

    // ---- gates + state update + h write (threads 0..127: e x s) ----
    if (tid < 128) {
      int e = tid >> 3, s = tid & 7;
      float zg4[4];
      #pragma unroll
      for (int r = 0; r < 4; ++r) {
        int cq = r * 4 + (e >> 2);
        int j  = e & 3;
        float sum = 0.f;
        #pragma unroll
        for (int w4 = 0; w4 < 4; ++w4)
          sum += zp[((w4 * 16 + cq) * Z9 + s) * 4 + j];
        zg4[r] = sum + bl_s[r * 16 + e];
      }
      float gi = 1.f / (1.f + expf(-zg4[0]));
      float gf = 1.f / (1.f + expf(-zg4[1]));
      float gg = tanhf(zg4[2]);
      float go = 1.f / (1.f + expf(-zg4[3]));
      float c = gf * c_lds[e * Z9 + s] + gi * gg;
      c_lds[e * Z9 + s] = c;
      float h = go * tanhf(c);
      size_t hidx = (((size_t)((it + 1) & 1) * NGRP + g) * NH_ + (w * 16 + e)) * SB + s;
      AST(hbuf + hidx, h);
    }
    __syncthreads();   // B6: drains vmcnt(0) -> h stores MALL-acked before counter add

    // ---- group sync: fence-free, MALL-mediated ----
    if (tid == 0) {
      __hip_atomic_fetch_add(cntg, 1, __ATOMIC_RELAXED, __HIP_MEMORY_SCOPE_AGENT);
      const int target = GWG * (it + 1);
      while (ALD(cntg) < target) __builtin_amdgcn_s_sleep(1);
    }
    __syncthreads();   // B7
  }
}

extern "C" void kernel_launch(void* const* d_in, const int* in_sizes, int n_in,
                              void* d_out, int out_size, void* d_ws, size_t ws_size,
                              hipStream_t stream)
{
  const float* X  = (const float*)d_in[0];
  const float* U  = (const float*)d_in[1];
  const float* Wk = (const float*)d_in[2];
  const float* Wr = (const float*)d_in[3];
  const float* bL = (const float*)d_in[4];
  const float* Wo = (const float*)d_in[5];
  const float* bo = (const float*)d_in[6];
  const float* Wc = (const float*)d_in[7];
  const float* bc = (const float*)d_in[8];
  float* out = (float*)d_out;

  int*   cnt  = (int*)d_ws;
  float* hbuf = (float*)((char*)d_ws + WS_HBUF);

  hipMemsetAsync(d_ws, 0, WS_HBUF, stream);   // zero counters each call

  hipFuncSetAttribute((const void*)earliest_coop,
                      hipFuncAttributeMaxDynamicSharedMemorySize, SMEM_BYTES);

  void* args[] = { (void*)&X, (void*)&U, (void*)&Wk, (void*)&Wr, (void*)&bL,
                   (void*)&Wo, (void*)&bo, (void*)&Wc, (void*)&bc, (void*)&out,
                   (void*)&cnt, (void*)&hbuf };
  hipError_t lerr = hipLaunchCooperativeKernel((const void*)earliest_coop,
                                               dim3(NGRP * GWG), dim3(TPW),
                                               args, SMEM_BYTES, stream);
  if (lerr != hipSuccess) {
    // Fallback: plain launch. 256 WGs x ~135KB LDS -> 1 WG/CU on 256 CUs,
    // co-resident in practice; same spin-sync semantics.
    hipLaunchKernelGGL(earliest_coop, dim3(NGRP * GWG), dim3(TPW), SMEM_BYTES, stream,
                       X, U, Wk, Wr, bL, Wo, bo, Wc, bc, out, cnt, hbuf);
  }
}